// Round 4
// baseline (6347.208 us; speedup 1.0000x reference)
//
#include <hip/hip_runtime.h>
#include <stdint.h>
#include <stdio.h>

// ---------------------------------------------------------------------------
// DilatedSparseRnnStack, round 8: round-6 structure + TLP + load ILP.
//  - Round-6 skeleton: per-phase per-wave flag barriers, PRE/POST split
//    (PRE of next phase + epilogue run between arrive() and wait()),
//    in-register cell, single-buffered outb. (Round-7 skew REGRESSED:
//    removed the overlap window and dropped ILP; reverted.)
//  - NEW: 512-thread WGs -> 8 waves/CU = 2 waves/SIMD. Wave owns 16 rows
//    (one M-tile); per-wave work halves; two waves/SIMD interleave L2 load
//    latency + VALU. Round-6 was 1 wave/SIMD with ~6k cy/phase of exposed
//    load latency -- the dominant cost.
//  - NEW: A-fragment prefetch arrays (static full unroll) -- all segment
//    loads issued before the MFMA chain; ob loads batched in POST; dC load
//    hoisted to PRE (own-WG data, no barrier needed).
//  - Cell: lanes lm<8 own (4 rows x 1 col); G0=acc0, G1=shfl_xor(acc0,8),
//    G2=acc1, G3=shfl_xor(acc1,8). C scratch indexed by oid=wv*32+quad*8+j.
// ---------------------------------------------------------------------------

typedef __attribute__((ext_vector_type(8))) short short8;
typedef __attribute__((ext_vector_type(4))) float f32x4;

#define DEVINL static __device__ __forceinline__

constexpr int TT = 256, BBATCH = 1024, INW = 64, HSW = 128, OSW = 128, NO = 8;
constexpr int ROWS = 128;                 // batch rows per cluster

constexpr int KLa[4]   = {192, 384, 448, 384};   // layer-0 dH folded: 320 -> 192
constexpr int DILa[4]  = {1, 3, 6, 12};
constexpr int PERa[4]  = {2, 4, 7, 13};   // h ring period = dil+1
// tiled weight layout: per (kt, half) a 1KB tile of 512 ushorts [lm][quad][8]
constexpr int WOFFa[4] = {0, 6144, 18432, 32768};   // ushort offsets
constexpr int WBYTES   = 90112;                     // 32 rows x 1408 k x 2B

constexpr int BIAS_B  = WBYTES;                    // 90,112
constexpr int WOUT_B  = BIAS_B + 512;              // 90,624
constexpr int WSTR    = 129;                       // wout pad
constexpr int BOUT_B  = WOUT_B + 8 * WSTR * 4;     // 94,752
constexpr int C3_B    = BOUT_B + 32;               // 94,784
constexpr int LDS_BYTES = C3_B + 12 * 256 * 16;    // 143,936 (<= 160 KiB)

// workspace layout (bytes)
//   [0,8192)      barrier flags: cluster c, wave w -> ws + c*1024 + w*128, 32 words
//   [8192,8704)   per-XCD rank counters (c*64)
constexpr size_t WSBASE    = 16384;
constexpr size_t BH_OFF[4] = {0, 65536, 196608, 425984}; // h rings (P_l slots of 128x128 bf16)
constexpr size_t OUTB_OFF  = 851968;                     // 4 x 128x128 bf16 (single-buffered)
constexpr size_t CB_OFF    = 983040;                     // C rings: layers 1,2
constexpr size_t C1_SZ     = 32 * 3 * 256 * 16;          // 393,216
constexpr size_t C2_SZ     = 32 * 6 * 256 * 16;          // 786,432
constexpr size_t CLSZ      = CB_OFF + C1_SZ + C2_SZ;     // 2,162,688 (~2.1 MB)
constexpr size_t WS_NEED   = WSBASE + 8 * CLSZ;          // ~17.3 MB

__host__ __device__ constexpr int seg_type(int L, int k) {
  // 0 = x (fp32), 1 = prev-layer out, 2 = prevH, 3 = dH
  if (L == 0) return k < 64 ? 0 : 2;                    // dH folded into prevH
  if (L == 1) return k < 128 ? 1 : (k < 256 ? 2 : 3);
  if (L == 2) return k < 128 ? 1 : (k < 192 ? 0 : (k < 320 ? 2 : 3));
  return k < 128 ? 1 : (k < 256 ? 2 : 3);
}
__host__ __device__ constexpr int seg_start(int L, int k) {
  if (L == 0) return k < 64 ? 0 : 64;
  if (L == 1) return k < 128 ? 0 : (k < 256 ? 128 : 256);
  if (L == 2) return k < 128 ? 0 : (k < 192 ? 128 : (k < 320 ? 192 : 320));
  return k < 128 ? 0 : (k < 256 ? 128 : 256);
}

template <int N> struct IC { static constexpr int value = N; };

DEVINL unsigned short f2bf(float f) {        // RNE fp32 -> bf16
  union { float f; uint32_t u; } v; v.f = f;
  return (unsigned short)((v.u + 0x7FFFu + ((v.u >> 16) & 1u)) >> 16);
}
DEVINL float bf2f(unsigned short h) {
  union { uint32_t u; float f; } v; v.u = ((uint32_t)h) << 16;
  return v.f;
}
DEVINL float sigm(float x)  { return 1.0f / (1.0f + __expf(-x)); }
DEVINL float tanh_(float x) { return 1.0f - 2.0f / (__expf(2.0f * x) + 1.0f); }

DEVINL short8 zero_s8() { short8 v; for (int i = 0; i < 8; i++) v[i] = 0; return v; }
DEVINL f32x4  zero_f4() { f32x4  v; for (int i = 0; i < 4; i++) v[i] = 0.f; return v; }

DEVINL f32x4 mfma16(short8 a, short8 b, f32x4 c) {
  return __builtin_amdgcn_mfma_f32_16x16x32_bf16(a, b, c, 0, 0, 0);
}

DEVINL short8 ld8f(const float* p) {         // 8 fp32 -> bf16x8 fragment
  const f32x4 u0 = *(const f32x4*)p;
  const f32x4 u1 = *(const f32x4*)(p + 4);
  short8 r;
  r[0] = (short)f2bf(u0[0]); r[1] = (short)f2bf(u0[1]);
  r[2] = (short)f2bf(u0[2]); r[3] = (short)f2bf(u0[3]);
  r[4] = (short)f2bf(u1[0]); r[5] = (short)f2bf(u1[1]);
  r[6] = (short)f2bf(u1[2]); r[7] = (short)f2bf(u1[3]);
  return r;
}

__global__ void __launch_bounds__(512, 1)
rnn_stack_kernel(const float* __restrict__ x,
                 const float* __restrict__ W0, const float* __restrict__ b0,
                 const float* __restrict__ W1, const float* __restrict__ b1,
                 const float* __restrict__ W2, const float* __restrict__ b2,
                 const float* __restrict__ W3, const float* __restrict__ b3,
                 const float* __restrict__ Wout, const float* __restrict__ bout,
                 float* __restrict__ yout, char* __restrict__ ws)
{
  extern __shared__ char smem[];
  unsigned short* wlds = (unsigned short*)smem;
  float* biasl = (float*)(smem + BIAS_B);
  float* woutl = (float*)(smem + WOUT_B);
  float* boutl = (float*)(smem + BOUT_B);
  float* c3l   = (float*)(smem + C3_B);     // [(slot*256 + oid)*4] f32 (owner-private)

  const int tid = threadIdx.x;

  // ---- runtime cluster formation: c = physical XCD, g = rank on that XCD ----
  __shared__ unsigned s_cg;
  if (tid == 0) {
    unsigned xcc;
    asm volatile("s_getreg_b32 %0, hwreg(HW_REG_XCC_ID)" : "=s"(xcc));
    xcc &= 7u;
    unsigned rank = __hip_atomic_fetch_add(
        (unsigned*)(ws + 8192 + (size_t)xcc * 64), 1u,
        __ATOMIC_RELAXED, __HIP_MEMORY_SCOPE_AGENT);
    s_cg = (xcc << 8) | (rank & 31u);
  }
  __syncthreads();
  const int c = __builtin_amdgcn_readfirstlane((int)(s_cg >> 8));
  const int g = __builtin_amdgcn_readfirstlane((int)(s_cg & 255));

  char* cb = ws + WSBASE + (size_t)c * CLSZ;
  unsigned short* bufH[4];
  unsigned short* outb[4];
#pragma unroll
  for (int l = 0; l < 4; l++) {
    bufH[l] = (unsigned short*)(cb + BH_OFF[l]);
    outb[l] = (unsigned short*)(cb + OUTB_OFF + (size_t)l * ROWS * OSW * 2);
  }
  float* bufC1 = (float*)(cb + CB_OFF + (size_t)g * (3 * 256 * 16));
  float* bufC2 = (float*)(cb + CB_OFF + C1_SZ + (size_t)g * (6 * 256 * 16));

  // ---- startup: weights -> tiled LDS (bf16); layer-0 dH block folded ----
  {
    const float* Wsrc[4] = {W0, W1, W2, W3};
    const float* bsrc[4] = {b0, b1, b2, b3};
    for (int l = 0; l < 4; l++) {
      const int K = KLa[l];
      const int Ksrc = (l == 0) ? 320 : K;             // W0 rows are length 320
      unsigned short* base = wlds + WOFFa[l];
      for (int n = 0; n < 32; n++) {
        const int grow = (n >> 3) * 256 + g * 8 + (n & 7);   // gate*SS + jglob
        const float* src = Wsrc[l] + (size_t)grow * Ksrc;
        for (int k = tid; k < K; k += 512) {
          float v = src[k];
          if (l == 0 && k >= 64) v += src[k + 128];    // fold W_dH into W_prevH
          // tile: [(kt*2 + half)*512 + lm*32 + quad*8 + e]
          base[((k >> 5) * 2 + (n >> 4)) * 512 + (n & 15) * 32 +
               ((k >> 3) & 3) * 8 + (k & 7)] = f2bf(v);
        }
      }
      if (tid < 32) biasl[l * 32 + tid] = bsrc[l][(tid >> 3) * 256 + g * 8 + (tid & 7)];
    }
    for (int i = tid; i < 8 * 128; i += 512) woutl[(i >> 7) * WSTR + (i & 127)] = Wout[i];
    if (tid < 8) boutl[tid] = bout[tid];
  }
  __syncthreads();           // the ONLY wg-wide sync; waves decouple after this

  const int wv = tid >> 6, lane = tid & 63, lm = lane & 15, quad = lane >> 4;
  const int m0 = wv * 16;          // wave's private 16 batch rows (one M-tile)
  const int j = lm & 7;            // owner's j-column (lanes lm<8 own cells)
  const int mrow = m0 + quad * 4;  // first of this owner's 4 rows
  const int oid = wv * 32 + quad * 8 + j;   // owner id 0..255 within WG

  // per-wave barrier flag block: 32 words (one per WG) for (cluster c, wave wv)
  unsigned* flg = (unsigned*)(ws + (size_t)c * 1024 + (size_t)wv * 128);

  f32x4 pc[4];                     // prevC (4 rows x owner's j), per layer
#pragma unroll
  for (int l = 0; l < 4; l++) pc[l] = zero_f4();

  f32x4 acc0, acc1;                // current-phase gate accumulators
  f32x4 dCreg = zero_f4();         // prefetched dC for the phase in flight

  auto arrive = [&](unsigned ep) {
    asm volatile("s_waitcnt vmcnt(0)" ::: "memory");   // publish stores in L2
    if (lane == 0)
      __hip_atomic_store(flg + g, ep, __ATOMIC_RELAXED, __HIP_MEMORY_SCOPE_AGENT);
  };
  auto waitbar = [&](unsigned ep) {
    asm volatile("" ::: "memory");
    for (;;) {
      unsigned v = __hip_atomic_load(flg + (lane & 31), __ATOMIC_RELAXED,
                                     __HIP_MEMORY_SCOPE_AGENT);
      if (__all((int)(v >= ep))) break;
      __builtin_amdgcn_s_sleep(1);
    }
    asm volatile("buffer_inv sc0" ::: "memory");   // L1 invalidate (XCD acquire)
  };

  // ---- PRE: acc init from bias; x/prevH/dH segments (barrier-independent);
  //      dC prefetch (own-WG data). All loads batched before the MFMA chain.
  auto pre = [&](auto Lc, int t) {
    constexpr int L = decltype(Lc)::value;
    constexpr int K = KLa[L];
    constexpr int NKT = K / 32;
    constexpr int DL = DILa[L];
    constexpr int P = PERa[L];
    const unsigned short* wl = wlds + WOFFa[L];
    const float bb0 = biasl[L * 32 + lm] + (lm < 8 ? 1.0f : 0.0f);  // fg bias +1
    const float bb1 = biasl[L * 32 + 16 + lm];
    acc0 = (f32x4){bb0, bb0, bb0, bb0};
    acc1 = (f32x4){bb1, bb1, bb1, bb1};
    dCreg = zero_f4();
    if constexpr (L == 1) { if (t >= DL) dCreg = *(const f32x4*)(bufC1 + ((size_t)(t % 3) * 256 + oid) * 4); }
    if constexpr (L == 2) { if (t >= DL) dCreg = *(const f32x4*)(bufC2 + ((size_t)(t % 6) * 256 + oid) * 4); }
    if constexpr (L == 3) { if (t >= DL) dCreg = *(const f32x4*)(c3l + ((size_t)(t % 12) * 256 + oid) * 4); }
    const unsigned short* phb =
        (t >= 1) ? bufH[L] + (size_t)((t - 1) % P) * ROWS * HSW : nullptr;
    const unsigned short* dhb =
        (t >= DL) ? bufH[L] + (size_t)((t - DL) % P) * ROWS * HSW : phb;
    const float* xb = x + ((size_t)t * BBATCH + (size_t)c * ROWS) * INW;
    short8 af[NKT];
#pragma unroll
    for (int kt = 0; kt < NKT; kt++) {
      const int sty = seg_type(L, kt * 32);
      if (sty == 1) continue;                    // ob segments belong to POST
      const int sst = seg_start(L, kt * 32);
      const int kloc = kt * 32 - sst + quad * 8;
      if (sty == 0) {
        af[kt] = ld8f(xb + (size_t)(m0 + lm) * INW + kloc);
      } else {
        const unsigned short* sb = (sty == 2) ? phb : dhb;
        af[kt] = sb ? *(const short8*)(sb + (size_t)(m0 + lm) * HSW + kloc)
                    : zero_s8();
      }
    }
#pragma unroll
    for (int kt = 0; kt < NKT; kt++) {
      if (seg_type(L, kt * 32) == 1) continue;
      const short8 bf0v = *(const short8*)(wl + (kt * 2 + 0) * 512 + lm * 32 + quad * 8);
      const short8 bf1v = *(const short8*)(wl + (kt * 2 + 1) * 512 + lm * 32 + quad * 8);
      acc0 = mfma16(af[kt], bf0v, acc0);
      acc1 = mfma16(af[kt], bf1v, acc1);
    }
  };

  // ---- POST: ob-segment MFMAs (batched loads), in-register cell, publish ----
  auto post = [&](auto Lc, int t) {
    constexpr int L = decltype(Lc)::value;
    constexpr int DL = DILa[L];
    constexpr int P = PERa[L];
    if constexpr (L > 0) {
      const unsigned short* wl = wlds + WOFFa[L];
      const unsigned short* ob = outb[L - 1];
      short8 af2[4];
#pragma unroll
      for (int kt = 0; kt < 4; kt++)
        af2[kt] = *(const short8*)(ob + (size_t)(m0 + lm) * HSW + kt * 32 + quad * 8);
#pragma unroll
      for (int kt = 0; kt < 4; kt++) {
        const short8 bf0v = *(const short8*)(wl + (kt * 2 + 0) * 512 + lm * 32 + quad * 8);
        const short8 bf1v = *(const short8*)(wl + (kt * 2 + 1) * 512 + lm * 32 + quad * 8);
        acc0 = mfma16(af2[kt], bf0v, acc0);
        acc1 = mfma16(af2[kt], bf1v, acc1);
      }
    }
    // gate exchange: owner lane (lm<8) pairs with lm+8
    f32x4 s0, s1;
#pragma unroll
    for (int r = 0; r < 4; r++) {
      s0[r] = __shfl_xor(acc0[r], 8);
      s1[r] = __shfl_xor(acc1[r], 8);
    }
    if (lm < 8) {                  // owners: 4 values (rows mrow..mrow+3, col j)
      const f32x4 G0 = acc0, G1 = s0, G2 = acc1, G3 = s1;
      const f32x4 pcv = pc[L];
      f32x4 nC, wh;
#pragma unroll
      for (int q = 0; q < 4; q++) {
        const float fg = sigm(G0[q]);        // bias & +1.0 already in acc init
        const float cd = tanh_(G1[q]);
        const float og = sigm(G3[q]);
        float wc;
        if constexpr (L == 0) {
          wc = pcv[q];                       // dil=1: alpha*prevC+(1-alpha)*prevC
        } else {
          const float al = sigm(G2[q]);
          wc = (t >= DL) ? (al * pcv[q] + (1.0f - al) * dCreg[q]) : pcv[q];
        }
        const float nc = (t >= 1) ? (fg * wc + (1.0f - fg) * cd) : cd;
        nC[q] = nc;
        wh[q] = og * nc;
      }
      if constexpr (L == 1) *(f32x4*)(bufC1 + ((size_t)(t % 3) * 256 + oid) * 4) = nC;
      if constexpr (L == 2) *(f32x4*)(bufC2 + ((size_t)(t % 6) * 256 + oid) * 4) = nC;
      if constexpr (L == 3) *(f32x4*)(c3l + ((size_t)(t % 12) * 256 + oid) * 4) = nC;
      pc[L] = nC;
      const int jg = g * 8 + j;
#pragma unroll
      for (int r = 0; r < 4; r++) {
        const unsigned short us = f2bf(wh[r]);
        const int row = mrow + r;
        if (g < 16) outb[L][(size_t)row * OSW + jg] = us;
        else bufH[L][((size_t)(t % P) * ROWS + row) * HSW + (jg - 128)] = us;
      }
    }
  };

  // ---- epilogue: wave computes y for row r = wv*16 + (g&15) (g and g+16
  //      duplicate the same row -> identical racing stores, benign) ----
  auto epilogue = [&](int tt) {
    const int r = m0 + (g & 15);
    const unsigned short* orow = outb[3] + (size_t)r * OSW;
    const int o = lane >> 3, s = lane & 7;
    const short8 v0 = *(const short8*)(orow + s * 16);
    const short8 v1 = *(const short8*)(orow + s * 16 + 8);
    float part = 0.f;
#pragma unroll
    for (int i = 0; i < 8; i++)
      part += bf2f((unsigned short)v0[i]) * woutl[o * WSTR + s * 16 + i];
#pragma unroll
    for (int i = 0; i < 8; i++)
      part += bf2f((unsigned short)v1[i]) * woutl[o * WSTR + s * 16 + 8 + i];
    part += __shfl_down(part, 4);
    part += __shfl_down(part, 2);
    part += __shfl_down(part, 1);
    if (s == 0)
      yout[((size_t)tt * BBATCH + (size_t)c * ROWS + r) * NO + o] = part + boutl[o];
  };

  // ---- main pipelined loop: POST(p) -> arrive(p) -> PRE(p+1) -> wait(p) ----
  pre(IC<0>{}, 0);
  for (int t = 0; t < TT; t++) {
    const unsigned pb = 4u * t;
    post(IC<0>{}, t); arrive(pb + 1); pre(IC<1>{}, t);
    if (t > 0) epilogue(t - 1);
    waitbar(pb + 1);
    post(IC<1>{}, t); arrive(pb + 2); pre(IC<2>{}, t); waitbar(pb + 2);
    post(IC<2>{}, t); arrive(pb + 3); pre(IC<3>{}, t); waitbar(pb + 3);
    post(IC<3>{}, t); arrive(pb + 4);
    if (t + 1 < TT) pre(IC<0>{}, t + 1);
    waitbar(pb + 4);
  }
  epilogue(TT - 1);
}

extern "C" void kernel_launch(void* const* d_in, const int* in_sizes, int n_in,
                              void* d_out, int out_size, void* d_ws, size_t ws_size,
                              hipStream_t stream) {
  const float* x    = (const float*)d_in[0];
  const float* W0   = (const float*)d_in[1];
  const float* b0   = (const float*)d_in[2];
  const float* W1   = (const float*)d_in[3];
  const float* b1   = (const float*)d_in[4];
  const float* W2   = (const float*)d_in[5];
  const float* b2   = (const float*)d_in[6];
  const float* W3   = (const float*)d_in[7];
  const float* b3   = (const float*)d_in[8];
  const float* Wout = (const float*)d_in[9];
  const float* bout = (const float*)d_in[10];
  float* out = (float*)d_out;
  char* ws = (char*)d_ws;

  if (ws_size < WS_NEED) {
    fprintf(stderr, "kernel_launch: ws_size %zu < needed %zu\n", ws_size, (size_t)WS_NEED);
    return;
  }

  // zero barrier flags + rank counters (ws is poisoned 0xAA before every launch)
  hipMemsetAsync(d_ws, 0, 16384, stream);

  hipError_t e = hipFuncSetAttribute((const void*)rnn_stack_kernel,
                                     hipFuncAttributeMaxDynamicSharedMemorySize,
                                     LDS_BYTES);
  if (e != hipSuccess) fprintf(stderr, "hipFuncSetAttribute: %d\n", (int)e);

  rnn_stack_kernel<<<dim3(256), dim3(512), LDS_BYTES, stream>>>(
      x, W0, b0, W1, b1, W2, b2, W3, b3, Wout, bout, out, ws);
  e = hipGetLastError();
  if (e != hipSuccess) fprintf(stderr, "launch error: %d\n", (int)e);
}